// Round 1
// baseline (782.296 us; speedup 1.0000x reference)
//
#include <hip/hip_runtime.h>
#include <math.h>

// CTC batch cost (keras ctc_batch_cost semantics), forward alpha recursion.
// B=128, T=512, C=1024, L=64, S=2L+1=129, blank = C-1 (last class).
// Inputs (setup_inputs dict order):
//   d_in[0] y_true       int32  [B,L]
//   d_in[1] y_pred       float  [B,T,C]  (softmax probs; we take log(p+eps))
//   d_in[2] input_length int32  [B,1]
//   d_in[3] label_length int32  [B,1]
// Output: float [B,1] = -logaddexp(alpha_T[2*lb], alpha_T[2*lb-1])

constexpr int Tmax  = 512;
constexpr int Cch   = 1024;
constexpr int Lm    = 64;
constexpr int Sext  = 2 * Lm + 1;   // 129
constexpr int BLANKC = Cch - 1;

#define NEGF (-1e9f)
#define EPSF (1e-7f)

__device__ __forceinline__ float lse3(float a, float b, float c) {
    float m = fmaxf(fmaxf(a, b), c);
    return m + logf(expf(a - m) + expf(b - m) + expf(c - m));
}

__global__ __launch_bounds__(128, 1) void ctc_fwd(
    const int*   __restrict__ y_true,
    const float* __restrict__ y_pred,
    const int*   __restrict__ in_len,
    const int*   __restrict__ lab_len,
    float*       __restrict__ out)
{
    const int b   = blockIdx.x;
    const int tid = threadIdx.x;

    __shared__ float alpha[2][Sext];
    __shared__ int   labsh[Sext];

    // build extended labels: blank at even s, labels at odd s
    for (int s = tid; s < Sext; s += 128)
        labsh[s] = (s & 1) ? y_true[b * Lm + (s >> 1)] : BLANKC;
    __syncthreads();

    int Tb = in_len[b];  Tb = Tb < 0 ? 0 : (Tb > Tmax ? Tmax : Tb);
    int lb = lab_len[b]; lb = lb < 0 ? 0 : (lb > Lm ? Lm : lb);
    const int Svalid = 2 * lb + 1;

    // thread owns state s0 = tid; thread 0 additionally owns s1 = 128.
    const int  s0   = tid;
    const int  s1   = tid + 128;
    const bool has1 = (s1 < Sext);          // only tid == 0
    const int  cls0 = labsh[s0];
    const int  cls1 = has1 ? labsh[s1] : 0;
    const bool skip0 = (s0 >= 2) && (cls0 != BLANKC) && (cls0 != labsh[s0 - 2]);
    const bool skip1 = has1 && (cls1 != BLANKC) && (cls1 != labsh[s1 - 2]);
    const bool val0  = s0 < Svalid;
    const bool val1  = s1 < Svalid;

    // virtual alpha_{-1}: mass only at s = 0
    alpha[0][s0] = (s0 == 0) ? 0.f : NEGF;
    if (has1) alpha[0][s1] = NEGF;
    __syncthreads();

    const float* __restrict__ base = y_pred + (size_t)b * Tmax * Cch;

    // software-pipelined emission prefetch, depth 4 (compile-time ring slots)
    float pf0[4], pf1[4];
#pragma unroll
    for (int i = 0; i < 4; ++i) {
        const float* prow = base + (size_t)i * Cch;   // i < 4 <= Tmax, safe
        pf0[i] = prow[cls0];
        pf1[i] = has1 ? prow[cls1] : 0.f;
    }

    int cur = 0;
    for (int t0 = 0; t0 < Tb; t0 += 4) {
#pragma unroll
        for (int i = 0; i < 4; ++i) {
            const int t = t0 + i;
            if (t >= Tb) break;   // Tb uniform across block

            const float e0 = logf(pf0[i] + EPSF);
            const float e1 = has1 ? logf(pf1[i] + EPSF) : 0.f;

            // issue prefetch for t+4 into this slot (row clamped for safety)
            {
                int tp = t + 4; int tr = tp < Tmax ? tp : Tmax - 1;
                const float* prow = base + (size_t)tr * Cch;
                pf0[i] = prow[cls0];
                if (has1) pf1[i] = prow[cls1];
            }

            const float* ac = alpha[cur];
            float r0;
            {
                const float a_s = ac[s0];
                const float a_1 = (s0 >= 1) ? ac[s0 - 1] : NEGF;
                const float a_2 = skip0 ? ac[s0 - 2] : NEGF;
                r0 = e0 + lse3(a_s, a_1, a_2);
                r0 = val0 ? r0 : NEGF;
            }
            float r1 = 0.f;
            if (has1) {
                const float a_s = ac[s1];
                const float a_1 = ac[s1 - 1];
                const float a_2 = skip1 ? ac[s1 - 2] : NEGF;
                r1 = e1 + lse3(a_s, a_1, a_2);
                r1 = val1 ? r1 : NEGF;
            }

            float* an = alpha[cur ^ 1];
            an[s0] = r0;
            if (has1) an[s1] = r1;
            __syncthreads();
            cur ^= 1;
        }
    }

    if (tid == 0) {
        int eb = 2 * lb;     if (eb > Sext - 1) eb = Sext - 1;
        int el = 2 * lb - 1; if (el < 0) el = 0;
        const float a1 = alpha[cur][eb];
        const float a2 = alpha[cur][el];
        const float m  = fmaxf(a1, a2);
        out[b] = -(m + logf(expf(a1 - m) + expf(a2 - m)));
    }
}

extern "C" void kernel_launch(void* const* d_in, const int* in_sizes, int n_in,
                              void* d_out, int out_size, void* d_ws, size_t ws_size,
                              hipStream_t stream) {
    const int*   y_true  = (const int*)  d_in[0];
    const float* y_pred  = (const float*)d_in[1];
    const int*   in_len  = (const int*)  d_in[2];
    const int*   lab_len = (const int*)  d_in[3];
    float*       out     = (float*)      d_out;

    ctc_fwd<<<dim3(128), dim3(128), 0, stream>>>(y_true, y_pred, in_len, lab_len, out);
}

// Round 3
// 597.044 us; speedup vs baseline: 1.3103x; 1.3103x over previous
//
#include <hip/hip_runtime.h>

// CTC batch cost (keras ctc_batch_cost), forward alpha recursion.
// B=128, T=512, C=1024, L=64, S=2L+1=129, blank = C-1.
//
// One wave (64 lanes) per batch element. Lane i owns extended states
// {2i, 2i+1}; lane 63 also owns state 128. Neighbor states (s-1, s-2)
// arrive via __shfl_up — no LDS, no __syncthreads, so the register
// emission-prefetch ring (depth 8) stays in flight across steps.
//
// Whole recursion runs in log2 domain (v_exp_f32 / v_log_f32 are base-2
// HW ops). ln-domain alpha = log2-domain alpha * ln2 exactly (all ops are
// max/+/lse — scale-equivariant), restored at the final loss.
//
// Inputs (setup_inputs order):
//   d_in[0] y_true       int32 [B,L]
//   d_in[1] y_pred       float [B,T,C]
//   d_in[2] input_length int32 [B,1]
//   d_in[3] label_length int32 [B,1]
// Output: float [B,1]

constexpr int Tmax   = 512;
constexpr int Cch    = 1024;
constexpr int Lm     = 64;
constexpr int BLANKC = Cch - 1;
constexpr int PF     = 8;          // prefetch depth (ring in registers)

#define NEGF (-1e9f)
#define EPSF (1e-7f)
#define LN2F (0.69314718055994530942f)

__device__ __forceinline__ float lae2(float a, float b) {
    float m = fmaxf(a, b);
    return m + __builtin_log2f(__builtin_exp2f(a - m) + __builtin_exp2f(b - m));
}
__device__ __forceinline__ float lse3_2(float a, float b, float c) {
    float m = fmaxf(fmaxf(a, b), c);
    return m + __builtin_log2f(__builtin_exp2f(a - m) +
                               __builtin_exp2f(b - m) +
                               __builtin_exp2f(c - m));
}

__global__ __launch_bounds__(64, 1) void ctc_wave(
    const int*   __restrict__ y_true,
    const float* __restrict__ y_pred,
    const int*   __restrict__ in_len,
    const int*   __restrict__ lab_len,
    float*       __restrict__ out)
{
    const int b    = blockIdx.x;
    const int lane = threadIdx.x;           // 0..63

    // label for odd state 2*lane+1
    const int cls = y_true[b * Lm + lane];

    int Tb = in_len[b];  Tb = Tb < 0 ? 0 : (Tb > Tmax ? Tmax : Tb);
    int lb = lab_len[b]; lb = lb < 0 ? 0 : (lb > Lm ? Lm : lb);

    // skip (s-2 -> s) for odd state 2i+1: allowed iff i>=1 and label differs
    const int  cls_prev = __shfl_up(cls, 1, 64);
    const bool skip     = (lane >= 1) && (cls != cls_prev);

    // validity masks (state s valid iff s < 2*lb+1)
    const bool val_lo = (lane <= lb);        // state 2*lane
    const bool val_hi = (lane <  lb);        // state 2*lane+1
    const bool val_ex = (lb == Lm);          // state 128 (lane 63 only)

    // virtual alpha_{-1}: mass only at state 0
    float a_lo = (lane == 0) ? 0.f : NEGF;
    float a_hi = NEGF;
    float a_ex = NEGF;

    const float* __restrict__ base = y_pred + (size_t)b * Tmax * Cch;

    // emission prefetch ring: label prob + blank prob per step
    float pf_c[PF], pf_b[PF];
#pragma unroll
    for (int i = 0; i < PF; ++i) {
        const float* row = base + (size_t)i * Cch;   // i < PF <= Tmax
        pf_c[i] = row[cls];
        pf_b[i] = row[BLANKC];
    }

    for (int t0 = 0; t0 < Tb; t0 += PF) {
#pragma unroll
        for (int i = 0; i < PF; ++i) {
            const int t = t0 + i;
            if (t >= Tb) break;              // Tb is wave-uniform

            const float e_c = __builtin_log2f(pf_c[i] + EPSF);
            const float e_b = __builtin_log2f(pf_b[i] + EPSF);

            // refill this ring slot for t+PF (row clamped; loads past Tb
            // are harmless, buffer extends to Tmax)
            {
                int tp = t + PF; int tr = tp < Tmax ? tp : Tmax - 1;
                const float* row = base + (size_t)tr * Cch;
                pf_c[i] = row[cls];
                pf_b[i] = row[BLANKC];
            }

            // neighbor states from previous lane
            float p_lo = __shfl_up(a_lo, 1, 64);
            float p_hi = __shfl_up(a_hi, 1, 64);
            if (lane == 0) { p_lo = NEGF; p_hi = NEGF; }

            // state 2i (blank): from self (2i) and 2i-1 (prev hi)
            float n_lo = e_b + lae2(a_lo, p_hi);
            // state 2i+1 (label): from self, 2i (local lo), 2i-1 via skip
            float n_hi = e_c + lse3_2(a_hi, a_lo, skip ? p_lo : NEGF);
            // state 128 (blank, lane 63): from self and 127 (local hi)
            float n_ex = e_b + lae2(a_ex, a_hi);

            a_lo = val_lo ? n_lo : NEGF;
            a_hi = val_hi ? n_hi : NEGF;
            a_ex = val_ex ? n_ex : NEGF;
        }
    }

    // gather final states: eb = 2*lb, el = 2*lb-1
    const float a_end_blank = (lb == Lm) ? __shfl(a_ex, 63, 64)
                                         : __shfl(a_lo, lb, 64);
    const int   el_lane     = (lb >= 1) ? (lb - 1) : 0;
    const float a_end_label = (lb >= 1) ? __shfl(a_hi, el_lane, 64)
                                        : __shfl(a_lo, 0, 64);  // clamp s=0

    if (lane == 0) {
        out[b] = -LN2F * lae2(a_end_blank, a_end_label);
    }
}

extern "C" void kernel_launch(void* const* d_in, const int* in_sizes, int n_in,
                              void* d_out, int out_size, void* d_ws, size_t ws_size,
                              hipStream_t stream) {
    const int*   y_true  = (const int*)  d_in[0];
    const float* y_pred  = (const float*)d_in[1];
    const int*   in_len  = (const int*)  d_in[2];
    const int*   lab_len = (const int*)  d_in[3];
    float*       out     = (float*)      d_out;

    ctc_wave<<<dim3(128), dim3(64), 0, stream>>>(y_true, y_pred, in_len, lab_len, out);
}